// Round 9
// baseline (137.736 us; speedup 1.0000x reference)
//
#include <hip/hip_runtime.h>
#include <hip/hip_bf16.h>

// SimpleDIN fused kernel v9 — v8 (A-frags in registers, static unrolls,
// 13.8 KB LDS) with launch_bounds(256,8): VGPR cap 64 (measured demand 48),
// targets 8 blocks/CU = 32 waves (100% occupancy) for latency hiding.
//
// Algebra: feats=[beh,tgt,beh*tgt,beh-tgt] (K=256) collapses:
//   feats @ W1 == beh @ W_eff + bias_eff   (K=64)
//   W_eff[d,j]  = W1[d,j] + tgt[d]*W1[128+d,j] + W1[192+d,j]
//   bias_eff[j] = b1[j] + sum_d tgt[d]*(W1[64+d,j] - W1[192+d,j])
// att_b2 cancels in softmax.

#define B_SZ  4096
#define S_SZ  200
#define D_SZ  64
#define H_SZ  80

typedef __attribute__((ext_vector_type(8))) short          bf16x8;
typedef __attribute__((ext_vector_type(8))) unsigned short u16x8;
typedef __attribute__((ext_vector_type(4))) float          f32x4;

struct __align__(16) Lds {
    unsigned short wefft[H_SZ * 64];   // 10240 B, swizzled bf16 [j][d]
    float w2l[H_SZ];
    float bias_eff[H_SZ];
    float scores[S_SZ];
    float x[2 * D_SZ];
    float h1[64];
    float pp[4 * 64];
    float red[8];
};                                      // ~13.8 KB

__device__ __forceinline__ int swz_gran(int row, int g) {
    return row * 64 + ((g ^ (row & 7)) << 3);      // u16 index of 16B granule
}
__device__ __forceinline__ int swz_elem(int row, int col) {
    return row * 64 + (((col >> 3) ^ (row & 7)) << 3) + (col & 7);
}
__device__ __forceinline__ float bits2f(unsigned int u) {
    union { unsigned int u; float f; } v; v.u = u; return v.f;
}
__device__ __forceinline__ float bfelem(bf16x8 v, int e) {
    return bits2f(((unsigned int)(unsigned short)v[e]) << 16);
}

extern "C" __global__ __launch_bounds__(256, 8)
void din_fused(const int* __restrict__ user_ids,
               const int* __restrict__ item_ids,
               const int* __restrict__ seq,
               const float* __restrict__ user_table,
               const float* __restrict__ item_table,
               const float* __restrict__ att_w1,
               const float* __restrict__ att_b1,
               const float* __restrict__ att_w2,
               const float* __restrict__ pred_w1,
               const float* __restrict__ pred_b1,
               const float* __restrict__ pred_w2,
               const float* __restrict__ pred_b2,
               const float* __restrict__ pred_w3,
               const float* __restrict__ pred_b3,
               float* __restrict__ out)
{
    __shared__ Lds L;
    const int b = blockIdx.x;
    const int t = threadIdx.x;

    const int wv = t >> 6;                  // wave 0..3
    const int l  = t & 63;
    const int lr = l & 15;                  // M-row / N-col within tile
    const int ks = l >> 4;                  // k-slot 0..3

    // ---- phase 0: small per-block loads ----
    const int uid = user_ids[b];
    const int iid = item_ids[b];
    if (t < 64) {
        L.x[t] = user_table[(size_t)uid * D_SZ + t];
    } else if (t < 64 + H_SZ) {
        L.w2l[t - 64] = att_w2[t - 64];
    }

    // ---- phase 1: gather A-frags global -> registers -> bf16 ----
    // FULLY STATIC unroll (no break): A0/A1 indices compile-time constant.
    // rows_ live range ends at the close of this block.
    bf16x8 A0[4], A1[4];
    {
        int rows_[4];
        #pragma unroll
        for (int i = 0; i < 4; ++i) {
            const int mt = wv + i * 4;
            const int srow = mt * 16 + lr;
            rows_[i] = (mt < 13 && srow < S_SZ) ? seq[b * S_SZ + srow] : -1;
        }
        #pragma unroll
        for (int i = 0; i < 4; ++i) {
            union { u16x8 u; bf16x8 bf; __hip_bfloat162 h2[4]; } c0, c1;
            if (rows_[i] >= 0) {
                const float4* src = reinterpret_cast<const float4*>(
                    item_table + (size_t)rows_[i] * D_SZ);
                const float4 q0 = src[2 * ks];
                const float4 q1 = src[2 * ks + 1];
                const float4 q2 = src[8 + 2 * ks];
                const float4 q3 = src[8 + 2 * ks + 1];
                c0.h2[0] = __float22bfloat162_rn(float2{q0.x, q0.y});
                c0.h2[1] = __float22bfloat162_rn(float2{q0.z, q0.w});
                c0.h2[2] = __float22bfloat162_rn(float2{q1.x, q1.y});
                c0.h2[3] = __float22bfloat162_rn(float2{q1.z, q1.w});
                c1.h2[0] = __float22bfloat162_rn(float2{q2.x, q2.y});
                c1.h2[1] = __float22bfloat162_rn(float2{q2.z, q2.w});
                c1.h2[2] = __float22bfloat162_rn(float2{q3.x, q3.y});
                c1.h2[3] = __float22bfloat162_rn(float2{q3.z, q3.w});
            } else {
                c0.u = (u16x8)0;
                c1.u = (u16x8)0;
            }
            A0[i] = c0.bf;
            A1[i] = c1.bf;
        }
    }

    // ---- phase 2: W_eff^T (bf16, swizzled) + bias_eff ----
    const float* tgtp = item_table + (size_t)iid * D_SZ;
    for (int i = t; i < 32 * H_SZ; i += 256) {
        const int dp = i / H_SZ;
        const int j  = i - dp * H_SZ;
        const int d  = dp * 2;
        const float2 tg = *reinterpret_cast<const float2*>(tgtp + d);
        const float w0 = att_w1[d * H_SZ + j]
                       + tg.x * att_w1[(128 + d) * H_SZ + j]
                       + att_w1[(192 + d) * H_SZ + j];
        const float w1 = att_w1[(d + 1) * H_SZ + j]
                       + tg.y * att_w1[(129 + d) * H_SZ + j]
                       + att_w1[(193 + d) * H_SZ + j];
        const __hip_bfloat162 hp = __float22bfloat162_rn(float2{w0, w1});
        *reinterpret_cast<__hip_bfloat162*>(&L.wefft[swz_elem(j, d)]) = hp;
    }
    if (t < 2 * H_SZ) {                     // 2 threads per j, 32 d each
        const int j = t >> 1;
        const int h = t & 1;
        float acc = h ? 0.f : att_b1[j];
        const int d0 = h * 32;
        #pragma unroll 4
        for (int d = d0; d < d0 + 32; ++d)
            acc += tgtp[d] * (att_w1[(64 + d) * H_SZ + j]
                            - att_w1[(192 + d) * H_SZ + j]);
        acc += __shfl_xor(acc, 1);
        if (h == 0) L.bias_eff[j] = acc;
    }
    __syncthreads();    // wefft + bias + w2l + x(user) ready

    // ---- phase 3: MFMA  C[s,j] = beh @ W_eff; logits = relu(C+b)·w2 ----
    #pragma unroll
    for (int i = 0; i < 4; ++i) {
        const int mt = wv + i * 4;
        if (mt < 13) {
            f32x4 acc[5];
            #pragma unroll
            for (int nt = 0; nt < 5; ++nt)
                acc[nt] = (f32x4){0.f, 0.f, 0.f, 0.f};
            #pragma unroll
            for (int nt = 0; nt < 5; ++nt) {
                const int j = nt * 16 + lr;
                const bf16x8 b0 = *reinterpret_cast<const bf16x8*>(
                    &L.wefft[swz_gran(j, ks)]);
                const bf16x8 b1 = *reinterpret_cast<const bf16x8*>(
                    &L.wefft[swz_gran(j, 4 + ks)]);
                acc[nt] = __builtin_amdgcn_mfma_f32_16x16x32_bf16(
                    A0[i], b0, acc[nt], 0, 0, 0);
                acc[nt] = __builtin_amdgcn_mfma_f32_16x16x32_bf16(
                    A1[i], b1, acc[nt], 0, 0, 0);
            }
            #pragma unroll
            for (int r = 0; r < 4; ++r) {
                const int s = mt * 16 + ks * 4 + r;
                float p = 0.f;
                #pragma unroll
                for (int nt = 0; nt < 5; ++nt) {
                    const int j = nt * 16 + lr;
                    const float h = acc[nt][r] + L.bias_eff[j];
                    p += fmaxf(h, 0.f) * L.w2l[j];
                }
                p += __shfl_xor(p, 1);
                p += __shfl_xor(p, 2);
                p += __shfl_xor(p, 4);
                p += __shfl_xor(p, 8);
                if (lr == 0 && s < S_SZ) L.scores[s] = p;
            }
        }
    }
    __syncthreads();

    // ---- phase 4: softmax over 200 logits ----
    const float raw = (t < S_SZ) ? L.scores[t] : -1e30f;
    float m = raw;
    #pragma unroll
    for (int off = 32; off; off >>= 1) m = fmaxf(m, __shfl_xor(m, off));
    if ((t & 63) == 0) L.red[t >> 6] = m;
    __syncthreads();
    m = fmaxf(fmaxf(L.red[0], L.red[1]), fmaxf(L.red[2], L.red[3]));
    const float e = (t < S_SZ) ? __expf(raw - m) : 0.f;
    if (t < S_SZ) L.scores[t] = e;
    float ssum = e;
    #pragma unroll
    for (int off = 32; off; off >>= 1) ssum += __shfl_xor(ssum, off);
    if ((t & 63) == 0) L.red[4 + (t >> 6)] = ssum;
    __syncthreads();
    const float inv = 1.f / (L.red[4] + L.red[5] + L.red[6] + L.red[7]);

    // ---- phase 5: pooled from A-frag registers (static indices) ----
    // guard srow<S_SZ alone is exact: mt>=13 => srow>=208>199
    {
        float pl[8], ph[8];
        #pragma unroll
        for (int e = 0; e < 8; ++e) { pl[e] = 0.f; ph[e] = 0.f; }
        #pragma unroll
        for (int i = 0; i < 4; ++i) {
            const int srow = (wv + i * 4) * 16 + lr;
            const float w = (srow < S_SZ) ? L.scores[srow] : 0.f;
            #pragma unroll
            for (int e = 0; e < 8; ++e) {
                pl[e] = fmaf(w, bfelem(A0[i], e), pl[e]);
                ph[e] = fmaf(w, bfelem(A1[i], e), ph[e]);
            }
        }
        #pragma unroll
        for (int msk = 1; msk < 16; msk <<= 1) {
            #pragma unroll
            for (int e = 0; e < 8; ++e) {
                pl[e] += __shfl_xor(pl[e], msk);
                ph[e] += __shfl_xor(ph[e], msk);
            }
        }
        if (lr == 0) {
            #pragma unroll
            for (int e = 0; e < 8; ++e) {
                L.pp[wv * 64 + 8 * ks + e]      = pl[e];
                L.pp[wv * 64 + 32 + 8 * ks + e] = ph[e];
            }
        }
    }
    __syncthreads();
    if (t < D_SZ) {
        L.x[D_SZ + t] = (L.pp[t] + L.pp[64 + t]
                       + L.pp[128 + t] + L.pp[192 + t]) * inv;
    }
    __syncthreads();

    // ---- phase 6: prediction MLP 128 -> 64 -> 32 -> 1 (all threads) ----
    {
        const int j  = t & 63;
        const int k0 = (t >> 6) * 32;
        float acc = 0.f;
        for (int k = k0; k < k0 + 32; ++k)
            acc = fmaf(L.x[k], pred_w1[k * 64 + j], acc);
        L.pp[(t >> 6) * 64 + j] = acc;
    }
    __syncthreads();
    if (t < 64) {
        const float a = pred_b1[t] + L.pp[t] + L.pp[64 + t]
                      + L.pp[128 + t] + L.pp[192 + t];
        L.h1[t] = fmaxf(a, 0.f);
    }
    __syncthreads();
    {
        const int j  = t & 31;
        const int k0 = (t >> 5) * 8;
        float acc = 0.f;
        #pragma unroll
        for (int k = k0; k < k0 + 8; ++k)
            acc = fmaf(L.h1[k], pred_w2[k * 32 + j], acc);
        L.pp[(t >> 5) * 32 + j] = acc;
    }
    __syncthreads();
    if (t < 32) {
        float a = pred_b2[t];
        #pragma unroll
        for (int q = 0; q < 8; ++q) a += L.pp[q * 32 + t];
        float p = fmaxf(a, 0.f) * pred_w3[t];
        p += __shfl_xor(p, 1);
        p += __shfl_xor(p, 2);
        p += __shfl_xor(p, 4);
        p += __shfl_xor(p, 8);
        p += __shfl_xor(p, 16);
        if (t == 0) {
            const float z = p + pred_b3[0];
            out[b] = 1.f / (1.f + __expf(-z));
        }
    }
}

extern "C" void kernel_launch(void* const* d_in, const int* in_sizes, int n_in,
                              void* d_out, int out_size, void* d_ws, size_t ws_size,
                              hipStream_t stream)
{
    const int*   user_ids   = (const int*)  d_in[0];
    const int*   item_ids   = (const int*)  d_in[1];
    const int*   seq        = (const int*)  d_in[2];
    const float* user_table = (const float*)d_in[3];
    const float* item_table = (const float*)d_in[4];
    const float* att_w1     = (const float*)d_in[5];
    const float* att_b1     = (const float*)d_in[6];
    const float* att_w2     = (const float*)d_in[7];
    // d_in[8] = att_b2: cancels in softmax, unused
    const float* pred_w1    = (const float*)d_in[9];
    const float* pred_b1    = (const float*)d_in[10];
    const float* pred_w2    = (const float*)d_in[11];
    const float* pred_b2    = (const float*)d_in[12];
    const float* pred_w3    = (const float*)d_in[13];
    const float* pred_b3    = (const float*)d_in[14];
    float* out = (float*)d_out;

    din_fused<<<B_SZ, 256, 0, stream>>>(user_ids, item_ids, seq,
                                        user_table, item_table,
                                        att_w1, att_b1, att_w2,
                                        pred_w1, pred_b1, pred_w2, pred_b2,
                                        pred_w3, pred_b3, out);
}

// Round 10
// 86.044 us; speedup vs baseline: 1.6008x; 1.6008x over previous
//
#include <hip/hip_runtime.h>
#include <hip/hip_bf16.h>

// SimpleDIN v10 — two-kernel design.
// Kernel P: pack G=W1a+W1d and C=W1c as swizzled bf16 (b-independent!) and
//           precompute bias_eff[b][j] = b1[j] + tgt_b·(W1b−W1d)[:,j].
// Kernel M: 4 independent waves per block (one b each). One barrier total
//           (after the 20KB G|C LDS copy); each wave: gather->MFMA
//           (h = beh·G + (beh⊙tgt)·C + bias) -> logits -> wave softmax ->
//           pool (re-read rows, L3-hot, coalesced) -> MLP. No convoy.
//
// ws layout: [0,20480) bf16 G|C pack ; byte 20480: float bias[4096*80]

typedef __attribute__((ext_vector_type(8))) short          bf16x8;
typedef __attribute__((ext_vector_type(8))) unsigned short u16x8;
typedef __attribute__((ext_vector_type(4))) float          f32x4;

__device__ __forceinline__ int swz_gran(int row, int g) {
    return row * 64 + ((g ^ (row & 7)) << 3);      // u16 index of 16B granule
}
__device__ __forceinline__ int swz_elem(int row, int col) {
    return row * 64 + (((col >> 3) ^ (row & 7)) << 3) + (col & 7);
}

// ---------------- Kernel P: prep (grid 257) ----------------
extern "C" __global__ __launch_bounds__(256)
void din_prep(const int* __restrict__ item_ids,
              const float* __restrict__ item_table,
              const float* __restrict__ att_w1,
              const float* __restrict__ att_b1,
              __hip_bfloat16* __restrict__ gcb,   // [10240] Gb|Cb swizzled
              float* __restrict__ bias_out)       // [4096*80]
{
    const int t = threadIdx.x;
    if (blockIdx.x == 256) {                      // pack block
        for (int i = t; i < 64 * 80; i += 256) {
            const int d = i / 80;
            const int j = i - d * 80;
            const float g = att_w1[d * 80 + j] + att_w1[(192 + d) * 80 + j];
            const float c = att_w1[(128 + d) * 80 + j];
            gcb[swz_elem(j, d)]        = __float2bfloat16(g);
            gcb[5120 + swz_elem(j, d)] = __float2bfloat16(c);
        }
        return;
    }
    __shared__ float wdiff[64 * 80];              // 20 KB
    __shared__ float tgts[16 * 64];               // 4 KB
    const int b0 = blockIdx.x * 16;
    for (int i = t; i < 64 * 80; i += 256) {
        const int d = i / 80;
        const int j = i - d * 80;
        wdiff[i] = att_w1[(64 + d) * 80 + j] - att_w1[(192 + d) * 80 + j];
    }
    for (int i = t; i < 16 * 64; i += 256) {
        const int bl = i >> 6, d = i & 63;
        tgts[i] = item_table[(size_t)item_ids[b0 + bl] * 64 + d];
    }
    __syncthreads();
    for (int i = t; i < 16 * 80; i += 256) {
        const int bl = i / 80;
        const int j  = i - bl * 80;
        float acc = att_b1[j];
        #pragma unroll 8
        for (int d = 0; d < 64; ++d)
            acc = fmaf(tgts[bl * 64 + d], wdiff[d * 80 + j], acc);
        bias_out[(size_t)(b0 + bl) * 80 + j] = acc;
    }
}

// ---------------- Kernel M: main (grid 1024, 4 b per block) ----------------
struct __align__(16) LdsW {
    unsigned short gcb[10240];    // 20480 B: Gb [0,5120) | Cb [5120,10240)
    float w2[80];                 // 320
    float biasw[4][80];           // 1280 (per wave)
    float wsc[4][208];            // 3328 (per-wave logits/exps)
    float aux[4][128];            // 2048 (per-wave MLP input)
    float h1s[4][64];             // 1024
};                                 // 28480 B -> 5 blocks/CU LDS-wise

extern "C" __global__ __launch_bounds__(256, 5)
void din_main(const int* __restrict__ user_ids,
              const int* __restrict__ item_ids,
              const int* __restrict__ seq,
              const float* __restrict__ user_table,
              const float* __restrict__ item_table,
              const float* __restrict__ att_w2,
              const float* __restrict__ pred_w1,
              const float* __restrict__ pred_b1,
              const float* __restrict__ pred_w2,
              const float* __restrict__ pred_b2,
              const float* __restrict__ pred_w3,
              const float* __restrict__ pred_b3,
              const unsigned short* __restrict__ gcb_g,
              const float* __restrict__ bias_g,
              float* __restrict__ out)
{
    __shared__ LdsW L;
    const int t  = threadIdx.x;
    const int wv = t >> 6;                  // wave = one batch element
    const int l  = t & 63;
    const int lr = l & 15;
    const int ks = l >> 4;
    const int b  = blockIdx.x * 4 + wv;

    // block-wide stage of shared constants (the ONLY barrier-protected data)
    {
        const u16x8* src = reinterpret_cast<const u16x8*>(gcb_g);
        u16x8* dst = reinterpret_cast<u16x8*>(L.gcb);
        #pragma unroll
        for (int i = 0; i < 5; ++i) dst[t + i * 256] = src[t + i * 256];
    }
    if (t < 80) L.w2[t] = att_w2[t];
    // per-wave bias (80 floats)
    L.biasw[wv][l] = bias_g[(size_t)b * 80 + l];
    if (l < 16) L.biasw[wv][64 + l] = bias_g[(size_t)b * 80 + 64 + l];

    // per-lane tgt slices for A2 = beh ⊙ tgt (k = ks*8.. and 32+ks*8..)
    const int iid = item_ids[b];
    const float4* tp = reinterpret_cast<const float4*>(
        item_table + (size_t)iid * 64);
    const float4 tg0 = tp[2 * ks], tg1 = tp[2 * ks + 1];
    const float4 tg2 = tp[8 + 2 * ks], tg3 = tp[8 + 2 * ks + 1];
    const int uid = user_ids[b];
    const float uem = user_table[(size_t)uid * 64 + l];
    const int* seqb = seq + b * 200;

    __syncthreads();                        // gcb/w2/bias ready

    // hoist epilogue constants (mt-invariant)
    float bias_r[5], w2_r[5];
    #pragma unroll
    for (int nt = 0; nt < 5; ++nt) {
        bias_r[nt] = L.biasw[wv][nt * 16 + lr];
        w2_r[nt]   = L.w2[nt * 16 + lr];
    }

    // ---- per-wave QK-style loop: 13 M-tiles, no barriers ----
    for (int mt = 0; mt < 13; ++mt) {
        const int srow = mt * 16 + lr;
        const bool val = srow < 200;
        const int row = val ? seqb[srow] : 0;
        const float4* rp = reinterpret_cast<const float4*>(
            item_table + (size_t)row * 64);
        float4 q0 = rp[2 * ks], q1 = rp[2 * ks + 1];
        float4 q2 = rp[8 + 2 * ks], q3 = rp[8 + 2 * ks + 1];
        if (!val) {
            q0 = make_float4(0.f, 0.f, 0.f, 0.f);
            q1 = make_float4(0.f, 0.f, 0.f, 0.f);
            q2 = make_float4(0.f, 0.f, 0.f, 0.f);
            q3 = make_float4(0.f, 0.f, 0.f, 0.f);
        }
        union { u16x8 u; bf16x8 bf; __hip_bfloat162 h2[4]; } A0, A1, A2, A3;
        A0.h2[0] = __float22bfloat162_rn(float2{q0.x, q0.y});
        A0.h2[1] = __float22bfloat162_rn(float2{q0.z, q0.w});
        A0.h2[2] = __float22bfloat162_rn(float2{q1.x, q1.y});
        A0.h2[3] = __float22bfloat162_rn(float2{q1.z, q1.w});
        A1.h2[0] = __float22bfloat162_rn(float2{q2.x, q2.y});
        A1.h2[1] = __float22bfloat162_rn(float2{q2.z, q2.w});
        A1.h2[2] = __float22bfloat162_rn(float2{q3.x, q3.y});
        A1.h2[3] = __float22bfloat162_rn(float2{q3.z, q3.w});
        A2.h2[0] = __float22bfloat162_rn(float2{q0.x * tg0.x, q0.y * tg0.y});
        A2.h2[1] = __float22bfloat162_rn(float2{q0.z * tg0.z, q0.w * tg0.w});
        A2.h2[2] = __float22bfloat162_rn(float2{q1.x * tg1.x, q1.y * tg1.y});
        A2.h2[3] = __float22bfloat162_rn(float2{q1.z * tg1.z, q1.w * tg1.w});
        A3.h2[0] = __float22bfloat162_rn(float2{q2.x * tg2.x, q2.y * tg2.y});
        A3.h2[1] = __float22bfloat162_rn(float2{q2.z * tg2.z, q2.w * tg2.w});
        A3.h2[2] = __float22bfloat162_rn(float2{q3.x * tg3.x, q3.y * tg3.y});
        A3.h2[3] = __float22bfloat162_rn(float2{q3.z * tg3.z, q3.w * tg3.w});

        f32x4 acc[5];
        #pragma unroll
        for (int nt = 0; nt < 5; ++nt)
            acc[nt] = (f32x4){0.f, 0.f, 0.f, 0.f};
        #pragma unroll
        for (int nt = 0; nt < 5; ++nt) {
            const int j = nt * 16 + lr;
            const bf16x8 g0 = *reinterpret_cast<const bf16x8*>(
                &L.gcb[swz_gran(j, ks)]);
            const bf16x8 g1 = *reinterpret_cast<const bf16x8*>(
                &L.gcb[swz_gran(j, 4 + ks)]);
            const bf16x8 c0 = *reinterpret_cast<const bf16x8*>(
                &L.gcb[5120 + swz_gran(j, ks)]);
            const bf16x8 c1 = *reinterpret_cast<const bf16x8*>(
                &L.gcb[5120 + swz_gran(j, 4 + ks)]);
            acc[nt] = __builtin_amdgcn_mfma_f32_16x16x32_bf16(A0.bf, g0, acc[nt], 0, 0, 0);
            acc[nt] = __builtin_amdgcn_mfma_f32_16x16x32_bf16(A1.bf, g1, acc[nt], 0, 0, 0);
            acc[nt] = __builtin_amdgcn_mfma_f32_16x16x32_bf16(A2.bf, c0, acc[nt], 0, 0, 0);
            acc[nt] = __builtin_amdgcn_mfma_f32_16x16x32_bf16(A3.bf, c1, acc[nt], 0, 0, 0);
        }
        #pragma unroll
        for (int r = 0; r < 4; ++r) {
            const int s = mt * 16 + ks * 4 + r;
            float p = 0.f;
            #pragma unroll
            for (int nt = 0; nt < 5; ++nt)
                p += fmaxf(acc[nt][r] + bias_r[nt], 0.f) * w2_r[nt];
            p += __shfl_xor(p, 1);
            p += __shfl_xor(p, 2);
            p += __shfl_xor(p, 4);
            p += __shfl_xor(p, 8);
            if (lr == 0 && s < 200) L.wsc[wv][s] = p;
        }
    }

    // ---- wave softmax over 200 logits (no barrier: same-wave LDS) ----
    const float v0 = L.wsc[wv][l];
    const float v1 = L.wsc[wv][64 + l];
    const float v2 = L.wsc[wv][128 + l];
    const float v3 = (l < 8) ? L.wsc[wv][192 + l] : -1e30f;
    float m = fmaxf(fmaxf(v0, v1), fmaxf(v2, v3));
    #pragma unroll
    for (int off = 1; off < 64; off <<= 1) m = fmaxf(m, __shfl_xor(m, off));
    const float e0 = __expf(v0 - m);
    const float e1 = __expf(v1 - m);
    const float e2 = __expf(v2 - m);
    const float e3 = (l < 8) ? __expf(v3 - m) : 0.f;
    L.wsc[wv][l] = e0;
    L.wsc[wv][64 + l] = e1;
    L.wsc[wv][128 + l] = e2;
    if (l < 8) L.wsc[wv][192 + l] = e3;
    float ssum = ((e0 + e1) + (e2 + e3));
    #pragma unroll
    for (int off = 1; off < 64; off <<= 1) ssum += __shfl_xor(ssum, off);
    const float inv = 1.f / ssum;

    // ---- pool: lane l owns d=l; coalesced row re-reads (L2/L3-hot) ----
    float p0 = 0.f, p1 = 0.f, p2 = 0.f, p3 = 0.f;
    for (int s = 0; s < 200; s += 4) {
        const int r0 = seqb[s],     r1 = seqb[s + 1];
        const int r2 = seqb[s + 2], r3 = seqb[s + 3];
        const float w0 = L.wsc[wv][s],     w1 = L.wsc[wv][s + 1];
        const float w2v = L.wsc[wv][s + 2], w3v = L.wsc[wv][s + 3];
        p0 = fmaf(w0,  item_table[(size_t)r0 * 64 + l], p0);
        p1 = fmaf(w1,  item_table[(size_t)r1 * 64 + l], p1);
        p2 = fmaf(w2v, item_table[(size_t)r2 * 64 + l], p2);
        p3 = fmaf(w3v, item_table[(size_t)r3 * 64 + l], p3);
    }
    const float pooled = ((p0 + p1) + (p2 + p3)) * inv;

    // ---- per-wave MLP 128 -> 64 -> 32 -> 1 ----
    L.aux[wv][l] = uem;
    L.aux[wv][64 + l] = pooled;
    float a0 = pred_b1[l], a1 = 0.f, a2 = 0.f, a3 = 0.f;
    #pragma unroll 4
    for (int k = 0; k < 128; k += 4) {
        a0 = fmaf(L.aux[wv][k],     pred_w1[k * 64 + l],       a0);
        a1 = fmaf(L.aux[wv][k + 1], pred_w1[(k + 1) * 64 + l], a1);
        a2 = fmaf(L.aux[wv][k + 2], pred_w1[(k + 2) * 64 + l], a2);
        a3 = fmaf(L.aux[wv][k + 3], pred_w1[(k + 3) * 64 + l], a3);
    }
    L.h1s[wv][l] = fmaxf((a0 + a1) + (a2 + a3), 0.f);
    const int j2 = l & 31;
    float c0 = pred_b2[j2], c1 = 0.f;
    #pragma unroll 4
    for (int k = 0; k < 64; k += 2) {
        c0 = fmaf(L.h1s[wv][k],     pred_w2[k * 32 + j2],       c0);
        c1 = fmaf(L.h1s[wv][k + 1], pred_w2[(k + 1) * 32 + j2], c1);
    }
    float p = fmaxf(c0 + c1, 0.f) * pred_w3[j2];
    p += __shfl_xor(p, 1);
    p += __shfl_xor(p, 2);
    p += __shfl_xor(p, 4);
    p += __shfl_xor(p, 8);
    p += __shfl_xor(p, 16);
    if (l == 0) {
        const float z = p + pred_b3[0];
        out[b] = 1.f / (1.f + __expf(-z));
    }
}

extern "C" void kernel_launch(void* const* d_in, const int* in_sizes, int n_in,
                              void* d_out, int out_size, void* d_ws, size_t ws_size,
                              hipStream_t stream)
{
    const int*   user_ids   = (const int*)  d_in[0];
    const int*   item_ids   = (const int*)  d_in[1];
    const int*   seq        = (const int*)  d_in[2];
    const float* user_table = (const float*)d_in[3];
    const float* item_table = (const float*)d_in[4];
    const float* att_w1     = (const float*)d_in[5];
    const float* att_b1     = (const float*)d_in[6];
    const float* att_w2     = (const float*)d_in[7];
    // d_in[8] = att_b2: cancels in softmax, unused
    const float* pred_w1    = (const float*)d_in[9];
    const float* pred_b1    = (const float*)d_in[10];
    const float* pred_w2    = (const float*)d_in[11];
    const float* pred_b2    = (const float*)d_in[12];
    const float* pred_w3    = (const float*)d_in[13];
    const float* pred_b3    = (const float*)d_in[14];
    float* out = (float*)d_out;

    __hip_bfloat16* gcb = (__hip_bfloat16*)d_ws;               // 20480 B
    float* bias_ws = (float*)((char*)d_ws + 20480);            // 4096*80 f32

    din_prep<<<257, 256, 0, stream>>>(item_ids, item_table, att_w1, att_b1,
                                      gcb, bias_ws);
    din_main<<<1024, 256, 0, stream>>>(user_ids, item_ids, seq,
                                       user_table, item_table, att_w2,
                                       pred_w1, pred_b1, pred_w2, pred_b2,
                                       pred_w3, pred_b3,
                                       (const unsigned short*)gcb, bias_ws,
                                       out);
}

// Round 11
// 75.084 us; speedup vs baseline: 1.8344x; 1.1460x over previous
//
#include <hip/hip_runtime.h>
#include <hip/hip_bf16.h>

// SimpleDIN v11 — prep + wave-per-b main with ONLINE fused pooling.
// Kernel P (65 blocks): pack G=W1a+W1d, C=W1c swizzled bf16 (b-independent);
//   bias_eff[b][j] = b1[j] + tgt_b·(W1b−W1d)[:,j]  (64 b's per block).
// Kernel M (1024 blocks, 4 waves = 4 b's): one barrier (20KB G|C copy), then
//   per wave: 13 MFMA tiles with logits + ONLINE softmax-pooling fused in the
//   loop (running max + rescale; pl/ph accumulate w·A-frag in-iteration) ->
//   butterfly -> MLP. No softmax phase, no pool re-gather pass.

typedef __attribute__((ext_vector_type(8))) short          bf16x8;
typedef __attribute__((ext_vector_type(8))) unsigned short u16x8;
typedef __attribute__((ext_vector_type(4))) float          f32x4;

__device__ __forceinline__ int swz_gran(int row, int g) {
    return row * 64 + ((g ^ (row & 7)) << 3);      // u16 index of 16B granule
}
__device__ __forceinline__ int swz_elem(int row, int col) {
    return row * 64 + (((col >> 3) ^ (row & 7)) << 3) + (col & 7);
}
__device__ __forceinline__ float bits2f(unsigned int u) {
    union { unsigned int u; float f; } v; v.u = u; return v.f;
}
__device__ __forceinline__ float bfelem(bf16x8 v, int e) {
    return bits2f(((unsigned int)(unsigned short)v[e]) << 16);
}

// ---------------- Kernel P: prep (grid 65) ----------------
extern "C" __global__ __launch_bounds__(256)
void din_prep(const int* __restrict__ item_ids,
              const float* __restrict__ item_table,
              const float* __restrict__ att_w1,
              const float* __restrict__ att_b1,
              __hip_bfloat16* __restrict__ gcb,   // [10240] Gb|Cb swizzled
              float* __restrict__ bias_out)       // [4096*80]
{
    const int t = threadIdx.x;
    if (blockIdx.x == 64) {                       // pack block
        for (int i = t; i < 64 * 80; i += 256) {
            const int d = i / 80;
            const int j = i - d * 80;
            const float g = att_w1[d * 80 + j] + att_w1[(192 + d) * 80 + j];
            const float c = att_w1[(128 + d) * 80 + j];
            gcb[swz_elem(j, d)]        = __float2bfloat16(g);
            gcb[5120 + swz_elem(j, d)] = __float2bfloat16(c);
        }
        return;
    }
    __shared__ float wdiff[64 * 80];              // 20 KB
    __shared__ float tgts[64 * 64];               // 16 KB (64 b's)
    const int b0 = blockIdx.x * 64;
    for (int i = t; i < 64 * 80; i += 256) {
        const int d = i / 80;
        const int j = i - d * 80;
        wdiff[i] = att_w1[(64 + d) * 80 + j] - att_w1[(192 + d) * 80 + j];
    }
    for (int i = t; i < 64 * 64; i += 256) {
        const int bl = i >> 6, d = i & 63;
        tgts[i] = item_table[(size_t)item_ids[b0 + bl] * 64 + d];
    }
    __syncthreads();
    for (int i = t; i < 64 * 80; i += 256) {
        const int bl = i / 80;
        const int j  = i - bl * 80;
        float acc = att_b1[j];
        #pragma unroll 8
        for (int d = 0; d < 64; ++d)
            acc = fmaf(tgts[bl * 64 + d], wdiff[d * 80 + j], acc);
        bias_out[(size_t)(b0 + bl) * 80 + j] = acc;
    }
}

// ---------------- Kernel M: main (grid 1024, 4 b per block) ----------------
struct __align__(16) LdsW {
    unsigned short gcb[10240];    // 20480 B: Gb [0,5120) | Cb [5120,10240)
    float w2[80];                 // 320
    float biasw[4][80];           // 1280 (per wave)
    float wsc[4][208];            // 3328 (per-wave logit exchange)
    float aux[4][128];            // 2048 (per-wave MLP input)
    float h1s[4][64];             // 1024
};                                 // 28480 B

extern "C" __global__ __launch_bounds__(256, 4)
void din_main(const int* __restrict__ user_ids,
              const int* __restrict__ item_ids,
              const int* __restrict__ seq,
              const float* __restrict__ user_table,
              const float* __restrict__ item_table,
              const float* __restrict__ att_w2,
              const float* __restrict__ pred_w1,
              const float* __restrict__ pred_b1,
              const float* __restrict__ pred_w2,
              const float* __restrict__ pred_b2,
              const float* __restrict__ pred_w3,
              const float* __restrict__ pred_b3,
              const unsigned short* __restrict__ gcb_g,
              const float* __restrict__ bias_g,
              float* __restrict__ out)
{
    __shared__ LdsW L;
    const int t  = threadIdx.x;
    const int wv = t >> 6;                  // wave = one batch element
    const int l  = t & 63;
    const int lr = l & 15;
    const int ks = l >> 4;
    const int b  = blockIdx.x * 4 + wv;

    // block-wide stage of shared constants (the ONLY barrier-protected data)
    {
        const u16x8* src = reinterpret_cast<const u16x8*>(gcb_g);
        u16x8* dst = reinterpret_cast<u16x8*>(L.gcb);
        #pragma unroll
        for (int i = 0; i < 5; ++i) dst[t + i * 256] = src[t + i * 256];
    }
    if (t < 80) L.w2[t] = att_w2[t];
    L.biasw[wv][l] = bias_g[(size_t)b * 80 + l];
    if (l < 16) L.biasw[wv][64 + l] = bias_g[(size_t)b * 80 + 64 + l];

    // per-lane tgt slices for A2 = beh ⊙ tgt
    const int iid = item_ids[b];
    const float4* tp = reinterpret_cast<const float4*>(
        item_table + (size_t)iid * 64);
    const float4 tg0 = tp[2 * ks], tg1 = tp[2 * ks + 1];
    const float4 tg2 = tp[8 + 2 * ks], tg3 = tp[8 + 2 * ks + 1];
    const int uid = user_ids[b];
    const float uem = user_table[(size_t)uid * 64 + l];
    const int* seqb = seq + b * 200;

    __syncthreads();                        // gcb/w2/bias ready

    // hoist epilogue constants (mt-invariant)
    float bias_r[5], w2_r[5];
    #pragma unroll
    for (int nt = 0; nt < 5; ++nt) {
        bias_r[nt] = L.biasw[wv][nt * 16 + lr];
        w2_r[nt]   = L.w2[nt * 16 + lr];
    }

    // ---- fused loop: 13 M-tiles, logits + online softmax-pooling ----
    float pl[8], ph[8];
    #pragma unroll
    for (int e = 0; e < 8; ++e) { pl[e] = 0.f; ph[e] = 0.f; }
    float mrun = -1e30f, ssum = 0.f;

    for (int mt = 0; mt < 13; ++mt) {
        const int srow = mt * 16 + lr;
        const bool val = srow < 200;
        const int row = val ? seqb[srow] : 0;
        const float4* rp = reinterpret_cast<const float4*>(
            item_table + (size_t)row * 64);
        float4 q0 = rp[2 * ks], q1 = rp[2 * ks + 1];
        float4 q2 = rp[8 + 2 * ks], q3 = rp[8 + 2 * ks + 1];
        if (!val) {
            q0 = make_float4(0.f, 0.f, 0.f, 0.f);
            q1 = make_float4(0.f, 0.f, 0.f, 0.f);
            q2 = make_float4(0.f, 0.f, 0.f, 0.f);
            q3 = make_float4(0.f, 0.f, 0.f, 0.f);
        }
        union { u16x8 u; bf16x8 bf; __hip_bfloat162 h2[4]; } A0, A1, A2, A3;
        A0.h2[0] = __float22bfloat162_rn(float2{q0.x, q0.y});
        A0.h2[1] = __float22bfloat162_rn(float2{q0.z, q0.w});
        A0.h2[2] = __float22bfloat162_rn(float2{q1.x, q1.y});
        A0.h2[3] = __float22bfloat162_rn(float2{q1.z, q1.w});
        A1.h2[0] = __float22bfloat162_rn(float2{q2.x, q2.y});
        A1.h2[1] = __float22bfloat162_rn(float2{q2.z, q2.w});
        A1.h2[2] = __float22bfloat162_rn(float2{q3.x, q3.y});
        A1.h2[3] = __float22bfloat162_rn(float2{q3.z, q3.w});
        A2.h2[0] = __float22bfloat162_rn(float2{q0.x * tg0.x, q0.y * tg0.y});
        A2.h2[1] = __float22bfloat162_rn(float2{q0.z * tg0.z, q0.w * tg0.w});
        A2.h2[2] = __float22bfloat162_rn(float2{q1.x * tg1.x, q1.y * tg1.y});
        A2.h2[3] = __float22bfloat162_rn(float2{q1.z * tg1.z, q1.w * tg1.w});
        A3.h2[0] = __float22bfloat162_rn(float2{q2.x * tg2.x, q2.y * tg2.y});
        A3.h2[1] = __float22bfloat162_rn(float2{q2.z * tg2.z, q2.w * tg2.w});
        A3.h2[2] = __float22bfloat162_rn(float2{q3.x * tg3.x, q3.y * tg3.y});
        A3.h2[3] = __float22bfloat162_rn(float2{q3.z * tg3.z, q3.w * tg3.w});

        f32x4 acc[5];
        #pragma unroll
        for (int nt = 0; nt < 5; ++nt)
            acc[nt] = (f32x4){0.f, 0.f, 0.f, 0.f};
        #pragma unroll
        for (int nt = 0; nt < 5; ++nt) {
            const int j = nt * 16 + lr;
            const bf16x8 g0 = *reinterpret_cast<const bf16x8*>(
                &L.gcb[swz_gran(j, ks)]);
            const bf16x8 g1 = *reinterpret_cast<const bf16x8*>(
                &L.gcb[swz_gran(j, 4 + ks)]);
            const bf16x8 c0 = *reinterpret_cast<const bf16x8*>(
                &L.gcb[5120 + swz_gran(j, ks)]);
            const bf16x8 c1 = *reinterpret_cast<const bf16x8*>(
                &L.gcb[5120 + swz_gran(j, 4 + ks)]);
            acc[nt] = __builtin_amdgcn_mfma_f32_16x16x32_bf16(A0.bf, g0, acc[nt], 0, 0, 0);
            acc[nt] = __builtin_amdgcn_mfma_f32_16x16x32_bf16(A1.bf, g1, acc[nt], 0, 0, 0);
            acc[nt] = __builtin_amdgcn_mfma_f32_16x16x32_bf16(A2.bf, c0, acc[nt], 0, 0, 0);
            acc[nt] = __builtin_amdgcn_mfma_f32_16x16x32_bf16(A3.bf, c1, acc[nt], 0, 0, 0);
        }

        // logits for this tile; invalid rows -> -1e30 (excluded from max)
        float pv[4];
        #pragma unroll
        for (int r = 0; r < 4; ++r) {
            const int s = mt * 16 + ks * 4 + r;
            float p = 0.f;
            #pragma unroll
            for (int nt = 0; nt < 5; ++nt)
                p += fmaxf(acc[nt][r] + bias_r[nt], 0.f) * w2_r[nt];
            p += __shfl_xor(p, 1);
            p += __shfl_xor(p, 2);
            p += __shfl_xor(p, 4);
            p += __shfl_xor(p, 8);
            if (s >= 200) p = -1e30f;
            pv[r] = p;
            if (lr == 0 && s < 200) L.wsc[wv][s] = p;
        }
        // wave max of this tile's logits
        float tmax = fmaxf(fmaxf(pv[0], pv[1]), fmaxf(pv[2], pv[3]));
        tmax = fmaxf(tmax, __shfl_xor(tmax, 16));
        tmax = fmaxf(tmax, __shfl_xor(tmax, 32));
        // online rescale (wave-uniform branch)
        if (tmax > mrun) {
            const float sc = __expf(mrun - tmax);   // 0 on first tile
            #pragma unroll
            for (int e = 0; e < 8; ++e) { pl[e] *= sc; ph[e] *= sc; }
            ssum *= sc;
            mrun = tmax;
        }
        // own-row weight from same-wave LDS exchange; accumulate pool
        float w = 0.f;
        if (val) w = __expf(L.wsc[wv][srow] - mrun);
        ssum += w;
        #pragma unroll
        for (int e = 0; e < 8; ++e) {
            pl[e] = fmaf(w, bfelem(A0.bf, e), pl[e]);
            ph[e] = fmaf(w, bfelem(A1.bf, e), ph[e]);
        }
    }

    // ---- reduce over lr (16 lanes); each ks-group covers all 200 rows ----
    #pragma unroll
    for (int msk = 1; msk < 16; msk <<= 1) {
        #pragma unroll
        for (int e = 0; e < 8; ++e) {
            pl[e] += __shfl_xor(pl[e], msk);
            ph[e] += __shfl_xor(ph[e], msk);
        }
        ssum += __shfl_xor(ssum, msk);
    }
    const float inv = 1.f / ssum;
    if (lr == 0) {
        #pragma unroll
        for (int e = 0; e < 8; ++e) {
            L.aux[wv][64 + 8 * ks + e]      = pl[e] * inv;
            L.aux[wv][64 + 32 + 8 * ks + e] = ph[e] * inv;
        }
    }
    L.aux[wv][l] = uem;

    // ---- per-wave MLP 128 -> 64 -> 32 -> 1 ----
    float a0 = pred_b1[l], a1 = 0.f, a2 = 0.f, a3 = 0.f;
    #pragma unroll 4
    for (int k = 0; k < 128; k += 4) {
        a0 = fmaf(L.aux[wv][k],     pred_w1[k * 64 + l],       a0);
        a1 = fmaf(L.aux[wv][k + 1], pred_w1[(k + 1) * 64 + l], a1);
        a2 = fmaf(L.aux[wv][k + 2], pred_w1[(k + 2) * 64 + l], a2);
        a3 = fmaf(L.aux[wv][k + 3], pred_w1[(k + 3) * 64 + l], a3);
    }
    L.h1s[wv][l] = fmaxf((a0 + a1) + (a2 + a3), 0.f);
    const int j2 = l & 31;
    float c0 = pred_b2[j2], c1 = 0.f;
    #pragma unroll 4
    for (int k = 0; k < 64; k += 2) {
        c0 = fmaf(L.h1s[wv][k],     pred_w2[k * 32 + j2],       c0);
        c1 = fmaf(L.h1s[wv][k + 1], pred_w2[(k + 1) * 32 + j2], c1);
    }
    float p = fmaxf(c0 + c1, 0.f) * pred_w3[j2];
    p += __shfl_xor(p, 1);
    p += __shfl_xor(p, 2);
    p += __shfl_xor(p, 4);
    p += __shfl_xor(p, 8);
    p += __shfl_xor(p, 16);
    if (l == 0) {
        const float z = p + pred_b3[0];
        out[b] = 1.f / (1.f + __expf(-z));
    }
}

extern "C" void kernel_launch(void* const* d_in, const int* in_sizes, int n_in,
                              void* d_out, int out_size, void* d_ws, size_t ws_size,
                              hipStream_t stream)
{
    const int*   user_ids   = (const int*)  d_in[0];
    const int*   item_ids   = (const int*)  d_in[1];
    const int*   seq        = (const int*)  d_in[2];
    const float* user_table = (const float*)d_in[3];
    const float* item_table = (const float*)d_in[4];
    const float* att_w1     = (const float*)d_in[5];
    const float* att_b1     = (const float*)d_in[6];
    const float* att_w2     = (const float*)d_in[7];
    // d_in[8] = att_b2: cancels in softmax, unused
    const float* pred_w1    = (const float*)d_in[9];
    const float* pred_b1    = (const float*)d_in[10];
    const float* pred_w2    = (const float*)d_in[11];
    const float* pred_b2    = (const float*)d_in[12];
    const float* pred_w3    = (const float*)d_in[13];
    const float* pred_b3    = (const float*)d_in[14];
    float* out = (float*)d_out;

    __hip_bfloat16* gcb = (__hip_bfloat16*)d_ws;               // 20480 B
    float* bias_ws = (float*)((char*)d_ws + 20480);            // 4096*80 f32

    din_prep<<<65, 256, 0, stream>>>(item_ids, item_table, att_w1, att_b1,
                                     gcb, bias_ws);
    din_main<<<1024, 256, 0, stream>>>(user_ids, item_ids, seq,
                                       user_table, item_table, att_w2,
                                       pred_w1, pred_b1, pred_w2, pred_b2,
                                       pred_w3, pred_b3,
                                       (const unsigned short*)gcb, bias_ws,
                                       out);
}